// Round 17
// baseline (340.689 us; speedup 1.0000x reference)
//
#include <hip/hip_runtime.h>
#include <math.h>

constexpr int BB  = 32;
constexpr int SQL = 2048;
constexpr int SKL = 2048;
constexpr int DD  = 64;

using f32x4 = __attribute__((ext_vector_type(4))) float;
using bfrag = __attribute__((ext_vector_type(8))) short;   // 8 bf16 = 4 VGPR
typedef unsigned long long u64;

static __device__ __forceinline__ unsigned short f2bf(float x) {
    unsigned u = __float_as_uint(x);
    u = u + 0x7FFFu + ((u >> 16) & 1u);          // round-nearest-even
    return (unsigned short)(u >> 16);
}
static __device__ __forceinline__ float bf2f(unsigned short h) {
    return __uint_as_float((unsigned)h << 16);
}

// async global->LDS, 16 B per lane (wave-uniform base + lane*16 dest)
static __device__ __forceinline__ void gld16(const void* g, void* l) {
    __builtin_amdgcn_global_load_lds(
        (const __attribute__((address_space(1))) void*)(size_t)g,
        (__attribute__((address_space(3))) void*)(unsigned)(size_t)l,
        16, 0, 0);
}

// ---- prepass: k fp32 -> swizzled bf16 hi/lo records (proven r6/r9/r13).
// Per (b,c): 256 B = [hi 128B][lo 128B]; 16-B groups XOR'd by ((c&7)<<4).
__global__ __launch_bounds__(256) void split_k_swz(
    const float* __restrict__ k, unsigned char* __restrict__ kswz)
{
    const int i0 = blockIdx.x * blockDim.x + threadIdx.x;  // (b,c,g)
    const int g  = i0 & 7;
    const int c  = (i0 >> 3) & 2047;
    const int b  = i0 >> 14;
    const float* kp = k + ((size_t)(b * 2048 + c)) * DD + g * 8;
    bfrag h, lo;
    #pragma unroll
    for (int j = 0; j < 8; ++j) {
        const float x = kp[j];
        const unsigned short hh = f2bf(x);
        h[j]  = (short)hh;
        lo[j] = (short)f2bf(x - bf2f(hh));
    }
    const int sw = (c & 7) << 4;
    unsigned char* rec = kswz + ((size_t)(b * 2048 + c)) * 256;
    *(bfrag*)(rec + ((g * 16) ^ sw))       = h;
    *(bfrag*)(rec + 128 + ((g * 16) ^ sw)) = lo;
}

#define MF(A, B, C) __builtin_amdgcn_mfma_f32_16x16x32_bf16((A), (B), (C), 0, 0, 0)
#define NIB4(M) ((unsigned)((M).x ? 1u:0u) | ((M).y ? 2u:0u) |                 \
                 ((M).z ? 4u:0u) | ((M).w ? 8u:0u))

// ---- main: block = 16 waves (1024 thr) = 32 q-rows x 2048 cols.
// Wave w owns 128 cols (8 tiles of 16), computes TWO 16-row groups per tile
// sharing k fragments. k via gld16 DMA into DEPTH-2 wave-private LDS ring;
// mask via direct per-lane int4 loads prefetched 2 tiles ahead in 2 static
// register sets. Per-iter VMEM group = {4 k + 2 mask}; steady vmcnt(6).
// sc[32] packed-bf16 scores -> ~115 VGPR, no spill (launch_bounds cap 128).
template<bool PRE>
__global__ __launch_bounds__(1024, 4) void sdpa_v17(
    const float* __restrict__ q, const float* __restrict__ k,
    const int* __restrict__ mask, const unsigned char* __restrict__ kswz,
    float* __restrict__ out)
{
    __shared__ char pool[16 * 8192 + 2048];   // 16 waves x 2 k-bufs + s_red

    const int t   = threadIdx.x;
    const int l   = t & 63;
    const int w   = t >> 6;                    // 0..15
    const int lr  = l & 15;
    const int lg  = l >> 4;
    const int bid = blockIdx.x;
    const int swz = (bid & 7) * 256 + (bid >> 3);   // bijective XCD chunking
    const int b   = swz >> 6;                       // batch
    const int r0  = (swz & 63) * 32;                // q-row base (32 rows)
    const int c0  = w * 128;                        // wave's col base
    const size_t row0 = (size_t)b * SQL + (size_t)(r0 + lr);        // g0 row
    const size_t row1 = row0 + 16;                                  // g1 row
    const int swk = (lr & 7) << 4;                  // k LDS swizzle key

    char* kseg = pool + w * 8192;
    const char*  ksrc = PRE ? (const char*)(kswz + ((size_t)b * SKL + c0) * 256) : nullptr;
    const float* kraw = PRE ? nullptr : k + (size_t)b * SKL * DD;
    const int*   mr0  = mask + row0 * SKL + c0 + lg * 4;
    const int*   mr1  = mask + row1 * SKL + c0 + lg * 4;

    // ---- q fragments FIRST (their waitcnt must not drain the stage queue)
    constexpr float QS = 0.18033688011112042f;      // 0.125 * log2(e)
    bfrag qh0a, ql0a, qh1a, ql1a;                   // group 0 (rows r0..+15)
    bfrag qh0b, ql0b, qh1b, ql1b;                   // group 1 (rows +16..31)
#define LOADQ(ROW, H0, L0, H1, L1)                                             \
    do {                                                                       \
        const float* _qp = q + (ROW) * DD + lg * 8;                            \
        const f32x4 _x0 = *(const f32x4*)_qp;                                  \
        const f32x4 _x1 = *(const f32x4*)(_qp + 4);                            \
        const f32x4 _y0 = *(const f32x4*)(_qp + 32);                           \
        const f32x4 _y1 = *(const f32x4*)(_qp + 36);                           \
        _Pragma("unroll")                                                      \
        for (int _j = 0; _j < 4; ++_j) {                                       \
            float _a = _x0[_j] * QS, _c = _x1[_j] * QS;                        \
            float _d = _y0[_j] * QS, _e = _y1[_j] * QS;                        \
            unsigned short _h;                                                 \
            _h = f2bf(_a); H0[_j]   = (short)_h; L0[_j]   = (short)f2bf(_a - bf2f(_h)); \
            _h = f2bf(_c); H0[_j+4] = (short)_h; L0[_j+4] = (short)f2bf(_c - bf2f(_h)); \
            _h = f2bf(_d); H1[_j]   = (short)_h; L1[_j]   = (short)f2bf(_d - bf2f(_h)); \
            _h = f2bf(_e); H1[_j+4] = (short)_h; L1[_j+4] = (short)f2bf(_e - bf2f(_h)); \
        }                                                                      \
    } while (0)
    LOADQ(row0, qh0a, ql0a, qh1a, ql1a);
    LOADQ(row1, qh0b, ql0b, qh1b, ql1b);
#undef LOADQ
    __builtin_amdgcn_sched_barrier(0);

#define STAGE(T)                                                               \
    do {                                                                       \
        char* _kd = kseg + (((T) & 1) << 12);                                  \
        if constexpr (PRE) {                                                   \
            const char* _ks = ksrc + (size_t)(T) * 4096;                       \
            gld16(_ks + l * 16,        _kd + l * 16);                          \
            gld16(_ks + 1024 + l * 16, _kd + 1024 + l * 16);                   \
            gld16(_ks + 2048 + l * 16, _kd + 2048 + l * 16);                   \
            gld16(_ks + 3072 + l * 16, _kd + 3072 + l * 16);                   \
        } else {                                                               \
            const float* _kc = kraw + (size_t)(c0 + (T) * 16 + lr) * DD;       \
            const f32x4 _a0 = *(const f32x4*)(_kc + lg * 8);                   \
            const f32x4 _a1 = *(const f32x4*)(_kc + lg * 8 + 4);               \
            const f32x4 _b0 = *(const f32x4*)(_kc + (lg + 4) * 8);             \
            const f32x4 _b1 = *(const f32x4*)(_kc + (lg + 4) * 8 + 4);         \
            bfrag _h, _o;                                                      \
            _Pragma("unroll")                                                  \
            for (int _j = 0; _j < 4; ++_j) {                                   \
                unsigned short _t2;                                            \
                _t2 = f2bf(_a0[_j]); _h[_j]   = (short)_t2;                    \
                _o[_j]   = (short)f2bf(_a0[_j] - bf2f(_t2));                   \
                _t2 = f2bf(_a1[_j]); _h[_j+4] = (short)_t2;                    \
                _o[_j+4] = (short)f2bf(_a1[_j] - bf2f(_t2));                   \
            }                                                                  \
            char* _rec = _kd + lr * 256;                                       \
            *(bfrag*)(_rec + ((lg * 16) ^ swk))       = _h;                    \
            *(bfrag*)(_rec + 128 + ((lg * 16) ^ swk)) = _o;                    \
            _Pragma("unroll")                                                  \
            for (int _j = 0; _j < 4; ++_j) {                                   \
                unsigned short _t2;                                            \
                _t2 = f2bf(_b0[_j]); _h[_j]   = (short)_t2;                    \
                _o[_j]   = (short)f2bf(_b0[_j] - bf2f(_t2));                   \
                _t2 = f2bf(_b1[_j]); _h[_j+4] = (short)_t2;                    \
                _o[_j+4] = (short)f2bf(_b1[_j] - bf2f(_t2));                   \
            }                                                                  \
            *(bfrag*)(_rec + (((lg + 4) * 16) ^ swk))       = _h;              \
            *(bfrag*)(_rec + 128 + (((lg + 4) * 16) ^ swk)) = _o;              \
        }                                                                      \
    } while (0)

    // ---- prologue: groups 0 and 1 ({4 k-gld16 + 2 mask-int4} each)
    int4 mA0, mB0, mA1, mB1;                 // 2 static mask sets (16 VGPR)
    STAGE(0);
    mA0 = *(const int4*)(mr0);      mB0 = *(const int4*)(mr1);
    STAGE(1);
    mA1 = *(const int4*)(mr0 + 16); mB1 = *(const int4*)(mr1 + 16);

    unsigned sc[32];                  // packed bf16 exp: [tile][g][pair]
    float psum0 = 0.f, psum1 = 0.f;

#define ITER(T, VMC, MA, MB)                                                   \
    do {                                                                       \
        if constexpr (PRE)                                                     \
            asm volatile("s_waitcnt vmcnt(" #VMC ")" ::: "memory");            \
        const char* _c = kseg + (((T) & 1) << 12) + lr * 256;                  \
        const bfrag _kh0 = *(const bfrag*)(_c + ((lg * 16) ^ swk));            \
        const bfrag _kh1 = *(const bfrag*)(_c + (((lg + 4) * 16) ^ swk));      \
        const bfrag _kl0 = *(const bfrag*)(_c + 128 + ((lg * 16) ^ swk));      \
        const bfrag _kl1 = *(const bfrag*)(_c + 128 + (((lg + 4) * 16) ^ swk));\
        int4 _mva, _mvb;                                                       \
        if constexpr (PRE) { _mva = MA; _mvb = MB; }                           \
        else {                                                                 \
            _mva = *(const int4*)(mr0 + (T) * 16);                             \
            _mvb = *(const int4*)(mr1 + (T) * 16);                             \
        }                                                                      \
        asm volatile("s_waitcnt lgkmcnt(0)" ::: "memory");                     \
        __builtin_amdgcn_sched_barrier(0);                                     \
        if constexpr ((T) + 2 < 8) {                                           \
            STAGE((T) + 2);                                                    \
            if constexpr (PRE) {                                               \
                MA = *(const int4*)(mr0 + ((T) + 2) * 16);                     \
                MB = *(const int4*)(mr1 + ((T) + 2) * 16);                     \
            }                                                                  \
        }                                                                      \
        /* group 0: hh chain + mixed chain */                                  \
        f32x4 _h = {0.f, 0.f, 0.f, 0.f};                                       \
        f32x4 _m = {0.f, 0.f, 0.f, 0.f};                                       \
        _h = MF(_kh0, qh0a, _h);  _m = MF(_kh0, ql0a, _m);                     \
        _h = MF(_kh1, qh1a, _h);  _m = MF(_kl0, qh0a, _m);                     \
        _m = MF(_kh1, ql1a, _m);  _m = MF(_kl1, qh1a, _m);                     \
        const f32x4 _s0 = _h + _m;                                             \
        /* group 1 */                                                          \
        f32x4 _h2 = {0.f, 0.f, 0.f, 0.f};                                      \
        f32x4 _m2 = {0.f, 0.f, 0.f, 0.f};                                      \
        _h2 = MF(_kh0, qh0b, _h2);  _m2 = MF(_kh0, ql0b, _m2);                 \
        _h2 = MF(_kh1, qh1b, _h2);  _m2 = MF(_kl0, qh0b, _m2);                 \
        _m2 = MF(_kh1, ql1b, _m2);  _m2 = MF(_kl1, qh1b, _m2);                 \
        const f32x4 _s1 = _h2 + _m2;                                           \
        const unsigned _n0 = NIB4(_mva);                                       \
        const unsigned _n1 = NIB4(_mvb);                                       \
        const float _e0 = (_n0 & 1u) ? exp2f(_s0[0]) : 0.f;                    \
        const float _e1 = (_n0 & 2u) ? exp2f(_s0[1]) : 0.f;                    \
        const float _e2 = (_n0 & 4u) ? exp2f(_s0[2]) : 0.f;                    \
        const float _e3 = (_n0 & 8u) ? exp2f(_s0[3]) : 0.f;                    \
        const float _f0 = (_n1 & 1u) ? exp2f(_s1[0]) : 0.f;                    \
        const float _f1 = (_n1 & 2u) ? exp2f(_s1[1]) : 0.f;                    \
        const float _f2 = (_n1 & 4u) ? exp2f(_s1[2]) : 0.f;                    \
        const float _f3 = (_n1 & 8u) ? exp2f(_s1[3]) : 0.f;                    \
        psum0 += (_e0 + _e1) + (_e2 + _e3);                                    \
        psum1 += (_f0 + _f1) + (_f2 + _f3);                                    \
        asm volatile("v_cvt_pk_bf16_f32 %0, %1, %2"                            \
                     : "=v"(sc[4 * (T)])     : "v"(_e0), "v"(_e1));            \
        asm volatile("v_cvt_pk_bf16_f32 %0, %1, %2"                            \
                     : "=v"(sc[4 * (T) + 1]) : "v"(_e2), "v"(_e3));            \
        asm volatile("v_cvt_pk_bf16_f32 %0, %1, %2"                            \
                     : "=v"(sc[4 * (T) + 2]) : "v"(_f0), "v"(_f1));            \
        asm volatile("v_cvt_pk_bf16_f32 %0, %1, %2"                            \
                     : "=v"(sc[4 * (T) + 3]) : "v"(_f2), "v"(_f3));            \
    } while (0)

    // ledger: group = {4 k + 2 mask}, depth-2 ring. vmcnt(6) = one newer
    // group outstanding -> group T complete. Last stage at T=5; tail: 6, 0.
    ITER(0, 6, mA0, mB0); ITER(1, 6, mA1, mB1);
    ITER(2, 6, mA0, mB0); ITER(3, 6, mA1, mB1);
    ITER(4, 6, mA0, mB0); ITER(5, 6, mA1, mB1);
    ITER(6, 6, mA0, mB0); ITER(7, 0, mA1, mB1);
#undef ITER
#undef STAGE

    // ---- row sums: lanes {l, l^16, l^32, l^48} share each q-row
    psum0 += __shfl_xor(psum0, 16, 64);
    psum0 += __shfl_xor(psum0, 32, 64);
    psum1 += __shfl_xor(psum1, 16, 64);
    psum1 += __shfl_xor(psum1, 32, 64);

    float* s_red = (float*)(pool + 16 * 8192);   // [wave][group][16]
    __syncthreads();
    if (l < 16) {
        s_red[w * 32 + lr]      = psum0;
        s_red[w * 32 + 16 + lr] = psum1;
    }
    __syncthreads();

    float tot0 = 0.f, tot1 = 0.f;
    #pragma unroll
    for (int ww = 0; ww < 16; ++ww) {
        tot0 += s_red[ww * 32 + lr];
        tot1 += s_red[ww * 32 + 16 + lr];
    }
    const float rinv0 = 1.0f / tot0;
    const float rinv1 = 1.0f / tot1;

    // ---- unpack, normalize, float4 stores (both row groups)
    float* op0 = out + row0 * SKL + c0 + lg * 4;
    float* op1 = out + row1 * SKL + c0 + lg * 4;
    #pragma unroll
    for (int T = 0; T < 8; ++T) {
        const unsigned pa = sc[4 * T], pb = sc[4 * T + 1];
        const unsigned pc = sc[4 * T + 2], pd = sc[4 * T + 3];
        f32x4 o0, o1;
        o0[0] = bf2f((unsigned short)(pa & 0xffffu)) * rinv0;
        o0[1] = bf2f((unsigned short)(pa >> 16))     * rinv0;
        o0[2] = bf2f((unsigned short)(pb & 0xffffu)) * rinv0;
        o0[3] = bf2f((unsigned short)(pb >> 16))     * rinv0;
        o1[0] = bf2f((unsigned short)(pc & 0xffffu)) * rinv1;
        o1[1] = bf2f((unsigned short)(pc >> 16))     * rinv1;
        o1[2] = bf2f((unsigned short)(pd & 0xffffu)) * rinv1;
        o1[3] = bf2f((unsigned short)(pd >> 16))     * rinv1;
        *reinterpret_cast<f32x4*>(op0 + T * 16) = o0;
        *reinterpret_cast<f32x4*>(op1 + T * 16) = o1;
    }
}

extern "C" void kernel_launch(void* const* d_in, const int* in_sizes, int n_in,
                              void* d_out, int out_size, void* d_ws, size_t ws_size,
                              hipStream_t stream) {
    const float* q    = (const float*)d_in[0];
    const float* k    = (const float*)d_in[1];
    const int*   mask = (const int*)d_in[2];
    float*       out  = (float*)d_out;

    const size_t KS_B = (size_t)BB * SKL * 256;       // 16.78 MB swizzled k

    dim3 grid(2048);    // 32 batches x 64 row-blocks, XCD-swizzled in-kernel

    if (ws_size >= KS_B) {
        unsigned char* ksp = (unsigned char*)d_ws;
        split_k_swz<<<2048, 256, 0, stream>>>(k, ksp);
        sdpa_v17<true><<<grid, 1024, 0, stream>>>(q, k, mask, ksp, out);
    } else {
        sdpa_v17<false><<<grid, 1024, 0, stream>>>(q, k, mask, nullptr, out);
    }
}

// Round 18
// 322.426 us; speedup vs baseline: 1.0566x; 1.0566x over previous
//
#include <hip/hip_runtime.h>
#include <math.h>

constexpr int BB  = 32;
constexpr int SQL = 2048;
constexpr int SKL = 2048;
constexpr int DD  = 64;

using f32x4 = __attribute__((ext_vector_type(4))) float;
using bfrag = __attribute__((ext_vector_type(8))) short;   // 8 bf16 = 4 VGPR
typedef unsigned long long u64;

static __device__ __forceinline__ unsigned short f2bf(float x) {
    unsigned u = __float_as_uint(x);
    u = u + 0x7FFFu + ((u >> 16) & 1u);          // round-nearest-even
    return (unsigned short)(u >> 16);
}
static __device__ __forceinline__ float bf2f(unsigned short h) {
    return __uint_as_float((unsigned)h << 16);
}

// async global->LDS, 16 B per lane (wave-uniform base + lane*16 dest)
static __device__ __forceinline__ void gld16(const void* g, void* l) {
    __builtin_amdgcn_global_load_lds(
        (const __attribute__((address_space(1))) void*)(size_t)g,
        (__attribute__((address_space(3))) void*)(unsigned)(size_t)l,
        16, 0, 0);
}

// ---- prepass: k fp32 -> swizzled bf16 hi/lo records (proven r6/r9/r13).
// Per (b,c): 256 B = [hi 128B][lo 128B]; 16-B groups XOR'd by ((c&7)<<4).
__global__ __launch_bounds__(256) void split_k_swz(
    const float* __restrict__ k, unsigned char* __restrict__ kswz)
{
    const int i0 = blockIdx.x * blockDim.x + threadIdx.x;  // (b,c,g)
    const int g  = i0 & 7;
    const int c  = (i0 >> 3) & 2047;
    const int b  = i0 >> 14;
    const float* kp = k + ((size_t)(b * 2048 + c)) * DD + g * 8;
    bfrag h, lo;
    #pragma unroll
    for (int j = 0; j < 8; ++j) {
        const float x = kp[j];
        const unsigned short hh = f2bf(x);
        h[j]  = (short)hh;
        lo[j] = (short)f2bf(x - bf2f(hh));
    }
    const int sw = (c & 7) << 4;
    unsigned char* rec = kswz + ((size_t)(b * 2048 + c)) * 256;
    *(bfrag*)(rec + ((g * 16) ^ sw))       = h;
    *(bfrag*)(rec + 128 + ((g * 16) ^ sw)) = lo;
}

#define MF(A, B, C) __builtin_amdgcn_mfma_f32_16x16x32_bf16((A), (B), (C), 0, 0, 0)

// ---- main: block = 8 waves (512 thr) = 16 q-rows x 2048 cols; wave w owns
// cols [w*256,(w+1)*256) = 16 tiles. Phase 1: block compresses ITS OWN 16-row
// mask slice (128 KB, coalesced) into 4 KB LDS bits -> 8 u64/lane in regs.
// Phase 2: r13-style MFMA loop, k via gld16 DMA depth-2 ring, vmcnt(4).
// LDS 68 KB -> 2 blocks/CU: one block's mask burst / store epilogue overlaps
// the other block's compute loop.
template<bool PRE>
__global__ __launch_bounds__(512, 4) void sdpa_v18(
    const float* __restrict__ q, const float* __restrict__ k,
    const int* __restrict__ mask, const unsigned char* __restrict__ kswz,
    float* __restrict__ out)
{
    __shared__ char kring[8][2][4096];     // 64 KB: per-wave depth-2 k ring
    __shared__ u64  bitlds[16][32];        // 4 KB: 16 rows x 2048 mask bits

    const int t   = threadIdx.x;
    const int l   = t & 63;
    const int w   = t >> 6;
    const int lr  = l & 15;
    const int lg  = l >> 4;
    const int bid = blockIdx.x;
    const int swz = (bid & 7) * 512 + (bid >> 3);   // bijective XCD chunking
    const int b   = swz >> 7;                       // batch
    const int r0  = (swz & 127) * 16;               // q-row base (16 rows)
    const int c0  = w * 256;                        // wave's col base
    const size_t rowg = (size_t)b * SQL + (size_t)(r0 + lr);  // lane's q-row
    const int swk = (lr & 7) << 4;                  // k LDS swizzle key

    // ================= phase 1: per-block mask compression =================
    // thread t: row = t>>5, col segment = (t&31)*64 .. +63  -> one u64
    {
        const int crow = t >> 5;
        const int cseg = t & 31;
        const int* mrow = mask + ((size_t)b * SQL + (size_t)(r0 + crow)) * SKL
                               + cseg * 64;
        u64 bits = 0;
        #pragma unroll
        for (int j = 0; j < 16; ++j) {
            const int4 v = *(const int4*)(mrow + j * 4);
            bits |= (u64)(v.x != 0 ? 1u : 0u) << (j * 4 + 0);
            bits |= (u64)(v.y != 0 ? 1u : 0u) << (j * 4 + 1);
            bits |= (u64)(v.z != 0 ? 1u : 0u) << (j * 4 + 2);
            bits |= (u64)(v.w != 0 ? 1u : 0u) << (j * 4 + 3);
        }
        bitlds[crow][cseg] = bits;
    }

    // ---- q fragments, scale (log2e/8) folded, hi/lo split
    constexpr float QS = 0.18033688011112042f;      // 0.125 * log2(e)
    bfrag qh0, ql0, qh1, ql1;
    {
        const float* qp = q + rowg * DD + lg * 8;
        const f32x4 x0 = *(const f32x4*)qp;
        const f32x4 x1 = *(const f32x4*)(qp + 4);
        const f32x4 y0 = *(const f32x4*)(qp + 32);
        const f32x4 y1 = *(const f32x4*)(qp + 36);
        #pragma unroll
        for (int j = 0; j < 4; ++j) {
            float a = x0[j] * QS, c = x1[j] * QS;
            float d = y0[j] * QS, e = y1[j] * QS;
            unsigned short h;
            h = f2bf(a); qh0[j]     = (short)h; ql0[j]     = (short)f2bf(a - bf2f(h));
            h = f2bf(c); qh0[j + 4] = (short)h; ql0[j + 4] = (short)f2bf(c - bf2f(h));
            h = f2bf(d); qh1[j]     = (short)h; ql1[j]     = (short)f2bf(d - bf2f(h));
            h = f2bf(e); qh1[j + 4] = (short)h; ql1[j + 4] = (short)f2bf(e - bf2f(h));
        }
    }

    __syncthreads();                                // bits visible to all

    // ---- this lane's 256 cols of row (r0+lr): 4 u64 bit words
    const u64 ma0 = bitlds[lr][w * 4 + 0];
    const u64 ma1 = bitlds[lr][w * 4 + 1];
    const u64 ma2 = bitlds[lr][w * 4 + 2];
    const u64 ma3 = bitlds[lr][w * 4 + 3];

    const char*  ksrc = PRE ? (const char*)(kswz + ((size_t)b * SKL + c0) * 256) : nullptr;
    const float* kraw = PRE ? nullptr : k + (size_t)b * SKL * DD;
    char* kseg = &kring[w][0][0];

#define STAGE(T)                                                               \
    do {                                                                       \
        char* _kd = kseg + (((T) & 1) << 12);                                  \
        if constexpr (PRE) {                                                   \
            const char* _ks = ksrc + (size_t)(T) * 4096;                       \
            gld16(_ks + l * 16,        _kd + l * 16);                          \
            gld16(_ks + 1024 + l * 16, _kd + 1024 + l * 16);                   \
            gld16(_ks + 2048 + l * 16, _kd + 2048 + l * 16);                   \
            gld16(_ks + 3072 + l * 16, _kd + 3072 + l * 16);                   \
        } else {                                                               \
            const float* _kc = kraw + (size_t)(c0 + (T) * 16 + lr) * DD;       \
            const f32x4 _a0 = *(const f32x4*)(_kc + lg * 8);                   \
            const f32x4 _a1 = *(const f32x4*)(_kc + lg * 8 + 4);               \
            const f32x4 _b0 = *(const f32x4*)(_kc + (lg + 4) * 8);             \
            const f32x4 _b1 = *(const f32x4*)(_kc + (lg + 4) * 8 + 4);         \
            bfrag _h, _o;                                                      \
            _Pragma("unroll")                                                  \
            for (int _j = 0; _j < 4; ++_j) {                                   \
                unsigned short _t2;                                            \
                _t2 = f2bf(_a0[_j]); _h[_j]   = (short)_t2;                    \
                _o[_j]   = (short)f2bf(_a0[_j] - bf2f(_t2));                   \
                _t2 = f2bf(_a1[_j]); _h[_j+4] = (short)_t2;                    \
                _o[_j+4] = (short)f2bf(_a1[_j] - bf2f(_t2));                   \
            }                                                                  \
            char* _rec = _kd + lr * 256;                                       \
            *(bfrag*)(_rec + ((lg * 16) ^ swk))       = _h;                    \
            *(bfrag*)(_rec + 128 + ((lg * 16) ^ swk)) = _o;                    \
            _Pragma("unroll")                                                  \
            for (int _j = 0; _j < 4; ++_j) {                                   \
                unsigned short _t2;                                            \
                _t2 = f2bf(_b0[_j]); _h[_j]   = (short)_t2;                    \
                _o[_j]   = (short)f2bf(_b0[_j] - bf2f(_t2));                   \
                _t2 = f2bf(_b1[_j]); _h[_j+4] = (short)_t2;                    \
                _o[_j+4] = (short)f2bf(_b1[_j] - bf2f(_t2));                   \
            }                                                                  \
            *(bfrag*)(_rec + (((lg + 4) * 16) ^ swk))       = _h;              \
            *(bfrag*)(_rec + 128 + (((lg + 4) * 16) ^ swk)) = _o;              \
        }                                                                      \
    } while (0)

    // ================= phase 2: MFMA loop over 16 k-tiles =================
    STAGE(0);
    STAGE(1);

    unsigned sc[32];                  // packed bf16 exp: [tile][pair]
    float psum = 0.f;

#define ITER(T, VMC, MW)                                                       \
    do {                                                                       \
        if constexpr (PRE)                                                     \
            asm volatile("s_waitcnt vmcnt(" #VMC ")" ::: "memory");            \
        const char* _c = kseg + (((T) & 1) << 12) + lr * 256;                  \
        const bfrag _kh0 = *(const bfrag*)(_c + ((lg * 16) ^ swk));            \
        const bfrag _kh1 = *(const bfrag*)(_c + (((lg + 4) * 16) ^ swk));      \
        const bfrag _kl0 = *(const bfrag*)(_c + 128 + ((lg * 16) ^ swk));      \
        const bfrag _kl1 = *(const bfrag*)(_c + 128 + (((lg + 4) * 16) ^ swk));\
        asm volatile("s_waitcnt lgkmcnt(0)" ::: "memory");                     \
        __builtin_amdgcn_sched_barrier(0);                                     \
        if constexpr ((T) + 2 < 16) STAGE((T) + 2);                            \
        /* hh chain + mixed chain */                                           \
        f32x4 _h = {0.f, 0.f, 0.f, 0.f};                                       \
        f32x4 _m = {0.f, 0.f, 0.f, 0.f};                                       \
        _h = MF(_kh0, qh0, _h);  _m = MF(_kh0, ql0, _m);                       \
        _h = MF(_kh1, qh1, _h);  _m = MF(_kl0, qh0, _m);                       \
        _m = MF(_kh1, ql1, _m);  _m = MF(_kl1, qh1, _m);                       \
        const f32x4 _s = _h + _m;                                              \
        const unsigned _n = (unsigned)((MW) >> (((T) & 3) * 16 + lg * 4)) & 0xFu; \
        const float _e0 = (_n & 1u) ? exp2f(_s[0]) : 0.f;                      \
        const float _e1 = (_n & 2u) ? exp2f(_s[1]) : 0.f;                      \
        const float _e2 = (_n & 4u) ? exp2f(_s[2]) : 0.f;                      \
        const float _e3 = (_n & 8u) ? exp2f(_s[3]) : 0.f;                      \
        psum += (_e0 + _e1) + (_e2 + _e3);                                     \
        asm volatile("v_cvt_pk_bf16_f32 %0, %1, %2"                            \
                     : "=v"(sc[2 * (T)])     : "v"(_e0), "v"(_e1));            \
        asm volatile("v_cvt_pk_bf16_f32 %0, %1, %2"                            \
                     : "=v"(sc[2 * (T) + 1]) : "v"(_e2), "v"(_e3));            \
    } while (0)

    // ledger: group = 4 k-gld16, depth-2 ring. vmcnt(4) = one newer group
    // outstanding -> group T complete. Last stage at T=13; tail: 4, 0.
    ITER(0,  4, ma0); ITER(1,  4, ma0); ITER(2,  4, ma0); ITER(3,  4, ma0);
    ITER(4,  4, ma1); ITER(5,  4, ma1); ITER(6,  4, ma1); ITER(7,  4, ma1);
    ITER(8,  4, ma2); ITER(9,  4, ma2); ITER(10, 4, ma2); ITER(11, 4, ma2);
    ITER(12, 4, ma3); ITER(13, 4, ma3); ITER(14, 4, ma3); ITER(15, 0, ma3);
#undef ITER
#undef STAGE

    // ---- row sums: lanes {l, l^16, l^32, l^48} share each q-row
    psum += __shfl_xor(psum, 16, 64);
    psum += __shfl_xor(psum, 32, 64);

    __syncthreads();                  // all bitlds reads done; alias s_red
    float* s_red = (float*)&bitlds[0][0];   // [wave][16]
    if (l < 16) s_red[w * 16 + lr] = psum;
    __syncthreads();

    float tot = 0.f;
    #pragma unroll
    for (int ww = 0; ww < 8; ++ww)
        tot += s_red[ww * 16 + lr];
    const float rinv = 1.0f / tot;

    // ---- unpack, normalize, float4 stores
    float* op = out + rowg * SKL + c0 + lg * 4;
    #pragma unroll
    for (int T = 0; T < 16; ++T) {
        const unsigned p01 = sc[2 * T];
        const unsigned p23 = sc[2 * T + 1];
        f32x4 o;
        o[0] = bf2f((unsigned short)(p01 & 0xffffu)) * rinv;
        o[1] = bf2f((unsigned short)(p01 >> 16))     * rinv;
        o[2] = bf2f((unsigned short)(p23 & 0xffffu)) * rinv;
        o[3] = bf2f((unsigned short)(p23 >> 16))     * rinv;
        *reinterpret_cast<f32x4*>(op + T * 16) = o;
    }
}

extern "C" void kernel_launch(void* const* d_in, const int* in_sizes, int n_in,
                              void* d_out, int out_size, void* d_ws, size_t ws_size,
                              hipStream_t stream) {
    const float* q    = (const float*)d_in[0];
    const float* k    = (const float*)d_in[1];
    const int*   mask = (const int*)d_in[2];
    float*       out  = (float*)d_out;

    const size_t KS_B = (size_t)BB * SKL * 256;   // 16.78 MB swizzled k

    dim3 grid(4096);    // 32 batches x 128 row-blocks, XCD-swizzled in-kernel

    if (ws_size >= KS_B) {
        unsigned char* ksp = (unsigned char*)d_ws;
        split_k_swz<<<2048, 256, 0, stream>>>(k, ksp);
        sdpa_v18<true><<<grid, 512, 0, stream>>>(q, k, mask, ksp, out);
    } else {
        sdpa_v18<false><<<grid, 512, 0, stream>>>(q, k, mask, nullptr, out);
    }
}